// Round 5
// baseline (89.865 us; speedup 1.0000x reference)
//
#include <hip/hip_runtime.h>
#include <hip/hip_bf16.h>
#include <math.h>

#define NN 8192
#define DD 64
#define WT 128                      // 64x64 wave-tiles per dim
#define TRI (WT * (WT + 1) / 2)     // 8256 per symmetric combo
#define TOTAL_WT (2 * TRI + WT * WT)  // 32896
#define NBLOCKS 2048
#define NWAVES (NBLOCKS * 4)        // 8192 persistent waves
#define NSLOT 32
#define SLOT_STRIDE 16              // floats -> 64B per slot (one cache line)

typedef __bf16 bf16x8 __attribute__((ext_vector_type(8)));
typedef float f32x4 __attribute__((ext_vector_type(4)));

#if defined(__has_builtin)
#if __has_builtin(__builtin_amdgcn_exp2f)
#define EXP2F __builtin_amdgcn_exp2f
#endif
#endif
#ifndef EXP2F
#define EXP2F exp2f
#endif

// ws layout:
//   [0,        1048576)  Xb  bf16 [8192][64]
//   [1048576,  2097152)  Zb  bf16 [8192][64]
//   [2097152, +32768)    na  f32  [8192]   ( = -log2(e) * ||x_i||^2 )
//   [+32768,  +65536)    nb  f32  [8192]
//   [+65536,  +71680)    partial f32 [3*NSLOT*SLOT_STRIDE]

__global__ void prep_kernel(const float* __restrict__ X, const float* __restrict__ Z,
                            __hip_bfloat16* __restrict__ Xb, __hip_bfloat16* __restrict__ Zb,
                            float* __restrict__ na, float* __restrict__ nb,
                            float* __restrict__ partial) {
    int gw = (blockIdx.x * blockDim.x + threadIdx.x) >> 6;  // row index in [0, 2N)
    int lane = threadIdx.x & 63;
    if (gw < 2 * NN) {
        const float* src = (gw < NN) ? (X + (size_t)gw * DD) : (Z + (size_t)(gw - NN) * DD);
        float v = src[lane];
        __hip_bfloat16 h = __float2bfloat16(v);
        float xr = __bfloat162float(h);
        __hip_bfloat16* dst = (gw < NN) ? (Xb + (size_t)gw * DD) : (Zb + (size_t)(gw - NN) * DD);
        dst[lane] = h;
        float s = xr * xr;
        #pragma unroll
        for (int off = 32; off; off >>= 1) s += __shfl_xor(s, off, 64);
        if (lane == 0) {
            if (gw < NN) na[gw] = -1.4426950408889634f * s;
            else         nb[gw - NN] = -1.4426950408889634f * s;
        }
    }
    if (blockIdx.x == 0) {
        for (int i = threadIdx.x; i < 3 * NSLOT * SLOT_STRIDE; i += blockDim.x) partial[i] = 0.f;
    }
}

// Persistent independent wave-tiles: each wave owns a 64x64 tile, grid-strides
// over the flat enumeration:
//   [0, 8256)        XX upper triangle (bj >= bi)
//   [8256, 16512)    ZZ upper triangle
//   [16512, 32896)   XZ full 128x128
// No __syncthreads in the main loop; TLP from 4 waves/SIMD hides L2 latency.
__global__ __launch_bounds__(256, 4) void mmd_kernel(
        const __hip_bfloat16* __restrict__ Xbh, const __hip_bfloat16* __restrict__ Zbh,
        const float* __restrict__ na, const float* __restrict__ nb,
        float* __restrict__ partial) {
    int tid = threadIdx.x;
    int wave = tid >> 6, lane = tid & 63;
    int lm = lane & 15;   // A-frag row / B-frag col / C col (within 16)
    int lk = lane >> 4;   // k-group of 8 / C row group of 4
    int gw = blockIdx.x * 4 + wave;
    const float C2 = 2.8853900817779268f;  // 2*log2(e)
    const __bf16* Xb = (const __bf16*)Xbh;
    const __bf16* Zb = (const __bf16*)Zbh;

    float s0 = 0.f, s1 = 0.f, s2 = 0.f;

    for (int t = gw; t < TOTAL_WT; t += NWAVES) {
        // ---- map flat id -> (combo, bi, bj) ----
        int combo, bi, bj;
        if (t < 2 * TRI) {
            int tt = t;
            combo = 0;
            if (tt >= TRI) { combo = 1; tt -= TRI; }
            int rr = (int)((257.0f - sqrtf(66049.0f - 8.0f * (float)tt)) * 0.5f);
            rr = rr < 0 ? 0 : (rr > 127 ? 127 : rr);
            while (rr > 0 && rr * (257 - rr) / 2 > tt) --rr;
            while ((rr + 1) * (256 - rr) / 2 <= tt) ++rr;
            bi = rr;
            bj = rr + (tt - rr * (257 - rr) / 2);
        } else {
            combo = 2;
            int rem = t - 2 * TRI;
            bi = rem >> 7;
            bj = rem & 127;
        }
        const __bf16* A  = (combo == 1) ? Zb : Xb;
        const __bf16* Bp = (combo == 0) ? Xb : Zb;
        const float* sa = (combo == 1) ? nb : na;
        const float* sb = (combo == 0) ? na : nb;
        int row0 = bi << 6, col0 = bj << 6;
        bool sym = (combo != 2);
        bool diag = sym && (bi == bj);
        float tileScale = (sym && bj > bi) ? 2.f : 1.f;

        // ---- MFMA: per-k-step fragment loads (keeps VGPR <= 128) ----
        f32x4 acc[4][4] = {};
        #pragma unroll
        for (int ks = 0; ks < 2; ++ks) {
            bf16x8 af[4], bfr[4];
            #pragma unroll
            for (int rt = 0; rt < 4; ++rt)
                af[rt] = *(const bf16x8*)(A + (size_t)(row0 + rt * 16 + lm) * DD + ks * 32 + lk * 8);
            #pragma unroll
            for (int ct = 0; ct < 4; ++ct)
                bfr[ct] = *(const bf16x8*)(Bp + (size_t)(col0 + ct * 16 + lm) * DD + ks * 32 + lk * 8);
            #pragma unroll
            for (int rt = 0; rt < 4; ++rt)
                #pragma unroll
                for (int ct = 0; ct < 4; ++ct)
                    acc[rt][ct] = __builtin_amdgcn_mfma_f32_16x16x32_bf16(
                        af[rt], bfr[ct], acc[rt][ct], 0, 0, 0);
        }

        // ---- norms ----
        f32x4 navv[4];
        float navmx[4], nbv[4];
        #pragma unroll
        for (int rt = 0; rt < 4; ++rt) {
            navv[rt] = *(const f32x4*)(sa + row0 + rt * 16 + lk * 4);
            navmx[rt] = fmaxf(fmaxf(navv[rt][0], navv[rt][1]), fmaxf(navv[rt][2], navv[rt][3]));
        }
        #pragma unroll
        for (int ct = 0; ct < 4; ++ct) nbv[ct] = sb[col0 + ct * 16 + lm];

        // ---- gated epilogue ----
        float lsum = 0.f;
        #pragma unroll
        for (int rt = 0; rt < 4; ++rt) {
            #pragma unroll
            for (int ct = 0; ct < 4; ++ct) {
                if (diag && rt > ct) continue;  // frag entirely below diagonal
                float fm = fmaxf(fmaxf(acc[rt][ct][0], acc[rt][ct][1]),
                                 fmaxf(acc[rt][ct][2], acc[rt][ct][3]));
                float fb = fmaf(fm, C2, navmx[rt] + nbv[ct]);
                if (__any(fb > -30.f)) {
                    float base = nbv[ct];
                    float a0 = fmaf(acc[rt][ct][0], C2, navv[rt][0] + base);
                    float a1 = fmaf(acc[rt][ct][1], C2, navv[rt][1] + base);
                    float a2 = fmaf(acc[rt][ct][2], C2, navv[rt][2] + base);
                    float a3 = fmaf(acc[rt][ct][3], C2, navv[rt][3] + base);
                    float e0 = EXP2F(fminf(a0, 0.f));
                    float e1 = EXP2F(fminf(a1, 0.f));
                    float e2 = EXP2F(fminf(a2, 0.f));
                    float e3 = EXP2F(fminf(a3, 0.f));
                    if (diag) {
                        int gcol = col0 + ct * 16 + lm;
                        int gr = row0 + rt * 16 + lk * 4;
                        e0 *= (gr + 0 < gcol) ? 2.f : ((gr + 0 == gcol) ? 1.f : 0.f);
                        e1 *= (gr + 1 < gcol) ? 2.f : ((gr + 1 == gcol) ? 1.f : 0.f);
                        e2 *= (gr + 2 < gcol) ? 2.f : ((gr + 2 == gcol) ? 1.f : 0.f);
                        e3 *= (gr + 3 < gcol) ? 2.f : ((gr + 3 == gcol) ? 1.f : 0.f);
                        lsum += (e0 + e1) + (e2 + e3);
                    } else {
                        lsum += tileScale * ((e0 + e1) + (e2 + e3));
                    }
                }
            }
        }
        if (combo == 0)      s0 += lsum;
        else if (combo == 1) s1 += lsum;
        else                 s2 += lsum;
    }

    // ---- flush: wave reduce -> LDS -> 3 spread global atomics per block ----
    #pragma unroll
    for (int off = 32; off; off >>= 1) {
        s0 += __shfl_xor(s0, off, 64);
        s1 += __shfl_xor(s1, off, 64);
        s2 += __shfl_xor(s2, off, 64);
    }
    __shared__ float bsum[3];
    if (tid < 3) bsum[tid] = 0.f;
    __syncthreads();
    if (lane == 0) {
        atomicAdd(&bsum[0], s0);
        atomicAdd(&bsum[1], s1);
        atomicAdd(&bsum[2], s2);
    }
    __syncthreads();
    if (tid < 3)
        atomicAdd(&partial[(tid * NSLOT + (blockIdx.x & (NSLOT - 1))) * SLOT_STRIDE], bsum[tid]);
}

__global__ void final_kernel(const float* __restrict__ partial, float* __restrict__ out) {
    __shared__ float s3[3];
    int tid = threadIdx.x;
    if (tid < 3) s3[tid] = 0.f;
    __syncthreads();
    if (tid < 3 * NSLOT) {
        float v = partial[tid * SLOT_STRIDE];
        atomicAdd(&s3[tid / NSLOT], v);
    }
    __syncthreads();
    if (tid == 0) {
        double inv = 1.0 / ((double)NN * (double)NN * 2.5066282746310002);  // N^2 * sqrt(2*pi)
        double mxx = (double)s3[0] * inv;
        double mzz = (double)s3[1] * inv;
        double mxz = (double)s3[2] * inv;
        double v = log(sqrt(mxx * mzz + 1e-5) / (mxz + 1e-5));
        out[0] = (float)v;
    }
}

extern "C" void kernel_launch(void* const* d_in, const int* in_sizes, int n_in,
                              void* d_out, int out_size, void* d_ws, size_t ws_size,
                              hipStream_t stream) {
    const float* X = (const float*)d_in[0];
    const float* Z = (const float*)d_in[1];
    char* ws = (char*)d_ws;
    __hip_bfloat16* Xb = (__hip_bfloat16*)(ws);
    __hip_bfloat16* Zb = (__hip_bfloat16*)(ws + 1048576);
    float* na = (float*)(ws + 2097152);
    float* nb = (float*)(ws + 2097152 + 32768);
    float* partial = (float*)(ws + 2097152 + 65536);

    hipLaunchKernelGGL(prep_kernel, dim3((2 * NN) / 4), dim3(256), 0, stream,
                       X, Z, Xb, Zb, na, nb, partial);
    hipLaunchKernelGGL(mmd_kernel, dim3(NBLOCKS), dim3(256), 0, stream, Xb, Zb, na, nb, partial);
    hipLaunchKernelGGL(final_kernel, dim3(1), dim3(128), 0, stream, partial, (float*)d_out);
}

// Round 6
// 87.867 us; speedup vs baseline: 1.0227x; 1.0227x over previous
//
#include <hip/hip_runtime.h>
#include <hip/hip_bf16.h>
#include <math.h>

#define NN 8192
#define DD 64
#define WT 128                      // 64x64 wave-tiles per dim
#define TRI (WT * (WT + 1) / 2)     // 8256 per symmetric combo
#define TOTAL_WT (2 * TRI + WT * WT)  // 32896
#define NBLOCKS 2048
#define NWAVES (NBLOCKS * 4)        // 8192 persistent waves
#define NSLOT 32
#define SLOT_STRIDE 16              // floats -> 64B per slot (one cache line)

typedef __bf16 bf16x8 __attribute__((ext_vector_type(8)));
typedef float f32x4 __attribute__((ext_vector_type(4)));

#if defined(__has_builtin)
#if __has_builtin(__builtin_amdgcn_exp2f)
#define EXP2F __builtin_amdgcn_exp2f
#endif
#endif
#ifndef EXP2F
#define EXP2F exp2f
#endif

// ws layout:
//   [0,        1048576)  Xb  bf16 [8192][64]
//   [1048576,  2097152)  Zb  bf16 [8192][64]
//   [2097152, +32768)    na  f32  [8192]   ( = -log2(e) * ||x_i||^2 )
//   [+32768,  +65536)    nb  f32  [8192]
//   [+65536,  +71680)    partial f32 [3*NSLOT*SLOT_STRIDE]

__global__ void prep_kernel(const float* __restrict__ X, const float* __restrict__ Z,
                            __hip_bfloat16* __restrict__ Xb, __hip_bfloat16* __restrict__ Zb,
                            float* __restrict__ na, float* __restrict__ nb,
                            float* __restrict__ partial) {
    int gw = (blockIdx.x * blockDim.x + threadIdx.x) >> 6;  // row index in [0, 2N)
    int lane = threadIdx.x & 63;
    if (gw < 2 * NN) {
        const float* src = (gw < NN) ? (X + (size_t)gw * DD) : (Z + (size_t)(gw - NN) * DD);
        float v = src[lane];
        __hip_bfloat16 h = __float2bfloat16(v);
        float xr = __bfloat162float(h);
        __hip_bfloat16* dst = (gw < NN) ? (Xb + (size_t)gw * DD) : (Zb + (size_t)(gw - NN) * DD);
        dst[lane] = h;
        float s = xr * xr;
        #pragma unroll
        for (int off = 32; off; off >>= 1) s += __shfl_xor(s, off, 64);
        if (lane == 0) {
            if (gw < NN) na[gw] = -1.4426950408889634f * s;
            else         nb[gw - NN] = -1.4426950408889634f * s;
        }
    }
    if (blockIdx.x == 0) {
        for (int i = threadIdx.x; i < 3 * NSLOT * SLOT_STRIDE; i += blockDim.x) partial[i] = 0.f;
    }
}

// Persistent independent wave-tiles: each wave owns a 64x64 tile, grid-strides
// over the flat enumeration:
//   [0, 8256)        XX upper triangle (bj >= bi)
//   [8256, 16512)    ZZ upper triangle
//   [16512, 32896)   XZ full 128x128
// No __syncthreads in the main loop; TLP from 3 blocks/CU hides L2 latency.
// min-waves=3 (NOT 4): VGPR cap 170 fits the ~150 live regs -> no scratch
// spills (R5's launch_bounds(256,4) capped at 128 and spilled acc -> 39MB
// of scratch writes).
__global__ __launch_bounds__(256, 3) void mmd_kernel(
        const __hip_bfloat16* __restrict__ Xbh, const __hip_bfloat16* __restrict__ Zbh,
        const float* __restrict__ na, const float* __restrict__ nb,
        float* __restrict__ partial) {
    int tid = threadIdx.x;
    int wave = tid >> 6, lane = tid & 63;
    int lm = lane & 15;   // A-frag row / B-frag col / C col (within 16)
    int lk = lane >> 4;   // k-group of 8 / C row group of 4
    int gw = blockIdx.x * 4 + wave;
    const float C2 = 2.8853900817779268f;  // 2*log2(e)
    const __bf16* Xb = (const __bf16*)Xbh;
    const __bf16* Zb = (const __bf16*)Zbh;

    float s0 = 0.f, s1 = 0.f, s2 = 0.f;

    for (int t = gw; t < TOTAL_WT; t += NWAVES) {
        // ---- map flat id -> (combo, bi, bj) ----
        int combo, bi, bj;
        if (t < 2 * TRI) {
            int tt = t;
            combo = 0;
            if (tt >= TRI) { combo = 1; tt -= TRI; }
            int rr = (int)((257.0f - sqrtf(66049.0f - 8.0f * (float)tt)) * 0.5f);
            rr = rr < 0 ? 0 : (rr > 127 ? 127 : rr);
            while (rr > 0 && rr * (257 - rr) / 2 > tt) --rr;
            while ((rr + 1) * (256 - rr) / 2 <= tt) ++rr;
            bi = rr;
            bj = rr + (tt - rr * (257 - rr) / 2);
        } else {
            combo = 2;
            int rem = t - 2 * TRI;
            bi = rem >> 7;
            bj = rem & 127;
        }
        const __bf16* A  = (combo == 1) ? Zb : Xb;
        const __bf16* Bp = (combo == 0) ? Xb : Zb;
        const float* sa = (combo == 1) ? nb : na;
        const float* sb = (combo == 0) ? na : nb;
        int row0 = bi << 6, col0 = bj << 6;
        bool sym = (combo != 2);
        bool diag = sym && (bi == bj);
        float tileScale = (sym && bj > bi) ? 2.f : 1.f;

        // ---- MFMA: per-k-step fragment loads (keeps live frag regs at 32) ----
        f32x4 acc[4][4] = {};
        #pragma unroll
        for (int ks = 0; ks < 2; ++ks) {
            bf16x8 af[4], bfr[4];
            #pragma unroll
            for (int rt = 0; rt < 4; ++rt)
                af[rt] = *(const bf16x8*)(A + (size_t)(row0 + rt * 16 + lm) * DD + ks * 32 + lk * 8);
            #pragma unroll
            for (int ct = 0; ct < 4; ++ct)
                bfr[ct] = *(const bf16x8*)(Bp + (size_t)(col0 + ct * 16 + lm) * DD + ks * 32 + lk * 8);
            #pragma unroll
            for (int rt = 0; rt < 4; ++rt)
                #pragma unroll
                for (int ct = 0; ct < 4; ++ct)
                    acc[rt][ct] = __builtin_amdgcn_mfma_f32_16x16x32_bf16(
                        af[rt], bfr[ct], acc[rt][ct], 0, 0, 0);
        }

        // ---- norms ----
        f32x4 navv[4];
        float navmx[4], nbv[4];
        #pragma unroll
        for (int rt = 0; rt < 4; ++rt) {
            navv[rt] = *(const f32x4*)(sa + row0 + rt * 16 + lk * 4);
            navmx[rt] = fmaxf(fmaxf(navv[rt][0], navv[rt][1]), fmaxf(navv[rt][2], navv[rt][3]));
        }
        #pragma unroll
        for (int ct = 0; ct < 4; ++ct) nbv[ct] = sb[col0 + ct * 16 + lm];

        // ---- gated epilogue ----
        float lsum = 0.f;
        #pragma unroll
        for (int rt = 0; rt < 4; ++rt) {
            #pragma unroll
            for (int ct = 0; ct < 4; ++ct) {
                if (diag && rt > ct) continue;  // frag entirely below diagonal
                float fm = fmaxf(fmaxf(acc[rt][ct][0], acc[rt][ct][1]),
                                 fmaxf(acc[rt][ct][2], acc[rt][ct][3]));
                float fb = fmaf(fm, C2, navmx[rt] + nbv[ct]);
                if (__any(fb > -30.f)) {
                    float base = nbv[ct];
                    float a0 = fmaf(acc[rt][ct][0], C2, navv[rt][0] + base);
                    float a1 = fmaf(acc[rt][ct][1], C2, navv[rt][1] + base);
                    float a2 = fmaf(acc[rt][ct][2], C2, navv[rt][2] + base);
                    float a3 = fmaf(acc[rt][ct][3], C2, navv[rt][3] + base);
                    float e0 = EXP2F(fminf(a0, 0.f));
                    float e1 = EXP2F(fminf(a1, 0.f));
                    float e2 = EXP2F(fminf(a2, 0.f));
                    float e3 = EXP2F(fminf(a3, 0.f));
                    if (diag) {
                        int gcol = col0 + ct * 16 + lm;
                        int gr = row0 + rt * 16 + lk * 4;
                        e0 *= (gr + 0 < gcol) ? 2.f : ((gr + 0 == gcol) ? 1.f : 0.f);
                        e1 *= (gr + 1 < gcol) ? 2.f : ((gr + 1 == gcol) ? 1.f : 0.f);
                        e2 *= (gr + 2 < gcol) ? 2.f : ((gr + 2 == gcol) ? 1.f : 0.f);
                        e3 *= (gr + 3 < gcol) ? 2.f : ((gr + 3 == gcol) ? 1.f : 0.f);
                        lsum += (e0 + e1) + (e2 + e3);
                    } else {
                        lsum += tileScale * ((e0 + e1) + (e2 + e3));
                    }
                }
            }
        }
        if (combo == 0)      s0 += lsum;
        else if (combo == 1) s1 += lsum;
        else                 s2 += lsum;
    }

    // ---- flush: wave reduce -> LDS -> 3 spread global atomics per block ----
    #pragma unroll
    for (int off = 32; off; off >>= 1) {
        s0 += __shfl_xor(s0, off, 64);
        s1 += __shfl_xor(s1, off, 64);
        s2 += __shfl_xor(s2, off, 64);
    }
    __shared__ float bsum[3];
    if (tid < 3) bsum[tid] = 0.f;
    __syncthreads();
    if (lane == 0) {
        atomicAdd(&bsum[0], s0);
        atomicAdd(&bsum[1], s1);
        atomicAdd(&bsum[2], s2);
    }
    __syncthreads();
    if (tid < 3)
        atomicAdd(&partial[(tid * NSLOT + (blockIdx.x & (NSLOT - 1))) * SLOT_STRIDE], bsum[tid]);
}

__global__ void final_kernel(const float* __restrict__ partial, float* __restrict__ out) {
    __shared__ float s3[3];
    int tid = threadIdx.x;
    if (tid < 3) s3[tid] = 0.f;
    __syncthreads();
    if (tid < 3 * NSLOT) {
        float v = partial[tid * SLOT_STRIDE];
        atomicAdd(&s3[tid / NSLOT], v);
    }
    __syncthreads();
    if (tid == 0) {
        double inv = 1.0 / ((double)NN * (double)NN * 2.5066282746310002);  // N^2 * sqrt(2*pi)
        double mxx = (double)s3[0] * inv;
        double mzz = (double)s3[1] * inv;
        double mxz = (double)s3[2] * inv;
        double v = log(sqrt(mxx * mzz + 1e-5) / (mxz + 1e-5));
        out[0] = (float)v;
    }
}

extern "C" void kernel_launch(void* const* d_in, const int* in_sizes, int n_in,
                              void* d_out, int out_size, void* d_ws, size_t ws_size,
                              hipStream_t stream) {
    const float* X = (const float*)d_in[0];
    const float* Z = (const float*)d_in[1];
    char* ws = (char*)d_ws;
    __hip_bfloat16* Xb = (__hip_bfloat16*)(ws);
    __hip_bfloat16* Zb = (__hip_bfloat16*)(ws + 1048576);
    float* na = (float*)(ws + 2097152);
    float* nb = (float*)(ws + 2097152 + 32768);
    float* partial = (float*)(ws + 2097152 + 65536);

    hipLaunchKernelGGL(prep_kernel, dim3((2 * NN) / 4), dim3(256), 0, stream,
                       X, Z, Xb, Zb, na, nb, partial);
    hipLaunchKernelGGL(mmd_kernel, dim3(NBLOCKS), dim3(256), 0, stream, Xb, Zb, na, nb, partial);
    hipLaunchKernelGGL(final_kernel, dim3(1), dim3(128), 0, stream, partial, (float*)d_out);
}